// Round 1
// 222.971 us; speedup vs baseline: 1.0792x; 1.0792x over previous
//
#include <hip/hip_runtime.h>
#include <math.h>

constexpr int D = 64;
constexpr int H = 4;

// ---------------------------------------------------------------------------
// R20: aggregate restructured to 4 edges per wave-step.  Lane = dim-QUAD
// (d=l&15 -> dims 4d..4d+3, exactly one uint4 of KVP), edge slot es=l>>4.
// Per step: 4 dot-fma + 2 shfl head-reduce (4 lanes/head) + exp + 4 acc-fma
// => ~4 VALU inst/edge/lane (was ~7), dependent steps per node halved.
// Main loop 16 edges/iter = 4 dwordx4 gathers in flight.  Final combine:
// shfl_xor 16/32 over edge slots, lanes 0-15 store float4.
// prep_w parallelized across 48 blocks (was 1 block, latency-serialized).
// Layouts (verified learn_hip m89/m120): A[m=lane&15][k=(lane>>4)*8+j],
// B[k=(lane>>4)*8+j][n=lane&15], C/D col=lane&15 row=(lane>>4)*4+reg.
// ---------------------------------------------------------------------------

typedef __attribute__((ext_vector_type(8))) short bf16x8;
typedef __attribute__((ext_vector_type(4))) float f32x4;

__device__ __forceinline__ unsigned short f32_to_bf16(float f) {
    const unsigned int u = __float_as_uint(f);
    return (unsigned short)((u + 0x7FFFu + ((u >> 16) & 1u)) >> 16);  // RNE
}
__device__ __forceinline__ float bf16_to_f32(unsigned short h) {
    return __uint_as_float(((unsigned int)h) << 16);
}
__device__ __forceinline__ float bf16lo_f32(unsigned int w) {   // bits 0-15
    return __uint_as_float(w << 16);
}
__device__ __forceinline__ float bf16hi_f32(unsigned int w) {   // bits 16-31
    return __uint_as_float(w & 0xFFFF0000u);
}

// ---------------------------------------------------------------------------
// Kernel 0: pre-split W into hi/lo MFMA B-fragment order with PERMUTED column
// map: fragment (mt, ct, ks, lane l, j) <- W_mt[ks*32+(l>>4)*8+j][4*(l&15)+ct]
// so MFMA acc[mt][ct] at lane m holds ORIGINAL output col 4m+ct.
// ---------------------------------------------------------------------------
__global__ __launch_bounds__(256) void prep_w_kernel(
    const float* __restrict__ Wq, const float* __restrict__ Wk,
    const float* __restrict__ Wv,
    unsigned short* __restrict__ WfH, unsigned short* __restrict__ WfL) {
    const float* W[3] = {Wq, Wk, Wv};
    for (int idx = blockIdx.x * 256 + threadIdx.x; idx < 3 * 4 * 2 * 64 * 8;
         idx += gridDim.x * 256) {
        const int j  = idx & 7;
        const int l  = (idx >> 3) & 63;
        const int ks = (idx >> 9) & 1;
        const int ct = (idx >> 10) & 3;
        const int mt = idx >> 12;
        const int krow = ks * 32 + (l >> 4) * 8 + j;
        const int col  = 4 * (l & 15) + ct;          // permuted column map
        const float w  = W[mt][krow * 64 + col];
        const unsigned short h = f32_to_bf16(w);
        WfH[idx] = h;
        WfL[idx] = f32_to_bf16(w - bf16_to_f32(h));
    }
}

// ---------------------------------------------------------------------------
// Kernel 1: QKV projection via split-precision MFMA (Ah*Bh + Ah*Bl + Al*Bh).
// Block = 4 waves; wave = 16 nodes.  Wf hi/lo staged in LDS (48 KB).
// Outputs: Q fp32 (dwordx4 per lane), KVP uint2 pairs (dwordx4 per lane).
// ---------------------------------------------------------------------------
__global__ __launch_bounds__(256) void qkv_kernel(
    const float* __restrict__ emb,
    const unsigned short* __restrict__ WfH,
    const unsigned short* __restrict__ WfL,
    int N, float* __restrict__ Q, unsigned int* __restrict__ KVP) {
    __shared__ unsigned short sH[12288];   // 24 KB
    __shared__ unsigned short sL[12288];   // 24 KB
    const int tid = threadIdx.x;

    {
        const uint4* gh = (const uint4*)WfH;
        const uint4* gl = (const uint4*)WfL;
        uint4* shh = (uint4*)sH;
        uint4* sll = (uint4*)sL;
        for (int k = tid; k < 1536; k += 256) {
            shh[k] = gh[k];
            sll[k] = gl[k];
        }
    }
    __syncthreads();

    const int wv = tid >> 6;
    const int l  = tid & 63;
    const int qd = l >> 4;              // quad 0..3
    const int m  = l & 15;
    const int n0 = blockIdx.x * 64 + wv * 16;

    // A fragments, split hi/lo: k = ks*32 + qd*8 + j
    bf16x8 aH[2], aL[2];
    {
        int node = n0 + m;
        if (node >= N) node = N - 1;
        const float4* ep = (const float4*)(emb + (size_t)node * 64);
#pragma unroll
        for (int ks = 0; ks < 2; ++ks) {
            const float4 a0 = ep[ks * 8 + qd * 2 + 0];
            const float4 a1 = ep[ks * 8 + qd * 2 + 1];
            const float f[8] = {a0.x, a0.y, a0.z, a0.w, a1.x, a1.y, a1.z, a1.w};
            bf16x8 fh, fl;
#pragma unroll
            for (int j = 0; j < 8; ++j) {
                const unsigned short h = f32_to_bf16(f[j]);
                fh[j] = (short)h;
                fl[j] = (short)f32_to_bf16(f[j] - bf16_to_f32(h));
            }
            aH[ks] = fh;
            aL[ks] = fl;
        }
    }

    f32x4 acc[3][4];
#pragma unroll
    for (int mt = 0; mt < 3; ++mt)
#pragma unroll
        for (int ct = 0; ct < 4; ++ct) acc[mt][ct] = (f32x4){0.f, 0.f, 0.f, 0.f};

#pragma unroll
    for (int mt = 0; mt < 3; ++mt) {
#pragma unroll
        for (int ct = 0; ct < 4; ++ct) {
#pragma unroll
            for (int ks = 0; ks < 2; ++ks) {
                const int fi = (((mt * 4 + ct) * 2 + ks) * 64 + l) * 8;
                bf16x8 bh = *(const bf16x8*)&sH[fi];
                bf16x8 bl = *(const bf16x8*)&sL[fi];
                acc[mt][ct] = __builtin_amdgcn_mfma_f32_16x16x32_bf16(
                    aH[ks], bh, acc[mt][ct], 0, 0, 0);
                acc[mt][ct] = __builtin_amdgcn_mfma_f32_16x16x32_bf16(
                    aH[ks], bl, acc[mt][ct], 0, 0, 0);
                acc[mt][ct] = __builtin_amdgcn_mfma_f32_16x16x32_bf16(
                    aL[ks], bh, acc[mt][ct], 0, 0, 0);
            }
        }
    }

    // Epilogue: lane holds original cols 4m+ct (ct=0..3), row = qd*4 + r.
#pragma unroll
    for (int r = 0; r < 4; ++r) {
        const int node = n0 + qd * 4 + r;
        if (node < N) {
            float4 oq;
            oq.x = acc[0][0][r]; oq.y = acc[0][1][r];
            oq.z = acc[0][2][r]; oq.w = acc[0][3][r];
            *(float4*)(Q + (size_t)node * 64 + 4 * m) = oq;

            uint4 kv;   // {kpack(4m,4m+1), vpack(..), kpack(4m+2,4m+3), vpack(..)}
            kv.x = (unsigned int)f32_to_bf16(acc[1][0][r]) |
                   ((unsigned int)f32_to_bf16(acc[1][1][r]) << 16);
            kv.y = (unsigned int)f32_to_bf16(acc[2][0][r]) |
                   ((unsigned int)f32_to_bf16(acc[2][1][r]) << 16);
            kv.z = (unsigned int)f32_to_bf16(acc[1][2][r]) |
                   ((unsigned int)f32_to_bf16(acc[1][3][r]) << 16);
            kv.w = (unsigned int)f32_to_bf16(acc[2][2][r]) |
                   ((unsigned int)f32_to_bf16(acc[2][3][r]) << 16);
            *(uint4*)(KVP + (size_t)node * 64 + 4 * m) = kv;   // uint2 idx 2m..2m+1
        }
    }
}

// --- Counting sort: histogram -> block sums -> block scan(+prefix) -> scatter

__global__ __launch_bounds__(256) void histo_kernel(
    const int* __restrict__ rows, int* __restrict__ cnt, int E) {
    const int e = blockIdx.x * 256 + threadIdx.x;
    if (e < E) atomicAdd(&cnt[rows[e]], 1);
}

__global__ __launch_bounds__(256) void block_sum_kernel(
    const int* __restrict__ cnt, int* __restrict__ bsum, int N) {
    __shared__ int s[256];
    const int tid = threadIdx.x;
    const int i   = blockIdx.x * 256 + tid;
    s[tid] = (i < N) ? cnt[i] : 0;
    __syncthreads();
    for (int st = 128; st > 0; st >>= 1) {
        if (tid < st) s[tid] += s[tid + st];
        __syncthreads();
    }
    if (tid == 0) bsum[blockIdx.x] = s[0];
}

// Per-chunk exclusive scan; global base computed IN-KERNEL from bsum.
__global__ __launch_bounds__(256) void block_scan_kernel(
    const int* __restrict__ cnt, const int* __restrict__ bsum,
    int* __restrict__ off, int* __restrict__ cur, int N, int E, int NB) {
    __shared__ int s[256];
    __shared__ int red[256];
    const int tid = threadIdx.x;
    const int bid = blockIdx.x;
    const int i   = bid * 256 + tid;

    // Global exclusive prefix of bsum for this block.
    int pacc = 0;
    for (int k = tid; k < NB; k += 256) {
        if (k < bid) pacc += bsum[k];
    }
    red[tid] = pacc;
    __syncthreads();
    for (int st = 128; st > 0; st >>= 1) {
        if (tid < st) red[tid] += red[tid + st];
        __syncthreads();
    }
    const int base = red[0];

    const int x = (i < N) ? cnt[i] : 0;
    s[tid] = x;
    __syncthreads();
    for (int offs = 1; offs < 256; offs <<= 1) {
        int v = 0;
        if (tid >= offs) v = s[tid - offs];
        __syncthreads();
        if (tid >= offs) s[tid] += v;
        __syncthreads();
    }
    if (i < N) {
        const int val = base + s[tid] - x;   // exclusive
        off[i] = val;
        cur[i] = val;
    }
    if (i == 0) off[N] = E;
}

__global__ __launch_bounds__(256) void scatter_kernel(
    const int* __restrict__ rows, const int* __restrict__ cols,
    int* __restrict__ cur, int* __restrict__ sc, int E) {
    const int e = blockIdx.x * 256 + threadIdx.x;
    if (e >= E) return;
    const int p = atomicAdd(&cur[rows[e]], 1);
    sc[p] = cols[e];
}

// ---------------------------------------------------------------------------
// Kernel 2: atomic-free aggregation, 4 edges per wave-step.
// lane l: d = l&15 (dim quad 4d..4d+3 = one uint4 of KVP), es = l>>4 (edge
// slot).  Head reduce = 2 shfl_xor over the 4-lane group (dh=16 = 4 lanes).
// Final cross-slot combine: shfl_xor 16/32; lanes 0-15 store float4.
// ---------------------------------------------------------------------------
__device__ __forceinline__ void agg_step(const uint4 kv, const float4 q4,
                                         bool ok, float& aN, float& a0,
                                         float& a1, float& a2, float& a3) {
    float pp = q4.x * bf16lo_f32(kv.x);
    pp = fmaf(q4.y, bf16hi_f32(kv.x), pp);
    pp = fmaf(q4.z, bf16lo_f32(kv.z), pp);
    pp = fmaf(q4.w, bf16hi_f32(kv.z), pp);
    pp += __shfl_xor(pp, 1);
    pp += __shfl_xor(pp, 2);
    float e = __expf(fminf(fmaxf(pp, -10.f), 10.f));
    e = ok ? e : 0.f;
    aN += e;
    a0 = fmaf(e, bf16lo_f32(kv.y), a0);
    a1 = fmaf(e, bf16hi_f32(kv.y), a1);
    a2 = fmaf(e, bf16lo_f32(kv.w), a2);
    a3 = fmaf(e, bf16hi_f32(kv.w), a3);
}

__global__ __launch_bounds__(256) void aggregate_kernel(
    const int* __restrict__ off, const int* __restrict__ sc,
    const float* __restrict__ Q, const unsigned int* __restrict__ KVP,
    float* __restrict__ out, int N) {
    const int t = blockIdx.x * 256 + threadIdx.x;
    const int n = t >> 6;
    const int l = t & 63;
    if (n >= N) return;
    const int d  = l & 15;              // dim quad
    const int es = l >> 4;              // edge slot 0..3

    const int off0 = off[n];
    const int off1 = off[n + 1];
    const float4 q4 = *(const float4*)(Q + (size_t)n * 64 + 4 * d);

    float aN = 0.f, a0 = 0.f, a1 = 0.f, a2 = 0.f, a3 = 0.f;
    int i = off0;

    // Main: 16 edges per iteration (4 steps, 4 dwordx4 gathers in flight).
    for (; i + 15 < off1; i += 16) {
        int c[4];
        uint4 kv[4];
#pragma unroll
        for (int j = 0; j < 4; ++j) c[j] = sc[i + 4 * j + es];
#pragma unroll
        for (int j = 0; j < 4; ++j)
            kv[j] = *(const uint4*)(KVP + (size_t)c[j] * 64 + 4 * d);
#pragma unroll
        for (int j = 0; j < 4; ++j)
            agg_step(kv[j], q4, true, aN, a0, a1, a2, a3);
    }
    // 4-edge steps.
    for (; i + 3 < off1; i += 4) {
        const int c0 = sc[i + es];
        const uint4 kv0 = *(const uint4*)(KVP + (size_t)c0 * 64 + 4 * d);
        agg_step(kv0, q4, true, aN, a0, a1, a2, a3);
    }
    // Masked tail (1..3 edges).
    if (i < off1) {
        const int idx = i + es;
        const bool ok = idx < off1;
        const int c0 = sc[ok ? idx : off1 - 1];
        const uint4 kv0 = *(const uint4*)(KVP + (size_t)c0 * 64 + 4 * d);
        agg_step(kv0, q4, ok, aN, a0, a1, a2, a3);
    }

    // Combine the four edge slots.
    aN += __shfl_xor(aN, 16);  aN += __shfl_xor(aN, 32);
    a0 += __shfl_xor(a0, 16);  a0 += __shfl_xor(a0, 32);
    a1 += __shfl_xor(a1, 16);  a1 += __shfl_xor(a1, 32);
    a2 += __shfl_xor(a2, 16);  a2 += __shfl_xor(a2, 32);
    a3 += __shfl_xor(a3, 16);  a3 += __shfl_xor(a3, 32);

    if (l < 16) {
        const float inv = 1.f / (aN + 1e-8f);
        float4 o;
        o.x = a0 * inv;
        o.y = a1 * inv;
        o.z = a2 * inv;
        o.w = a3 * inv;
        *(float4*)(out + (size_t)n * 64 + 4 * d) = o;
    }
}

extern "C" void kernel_launch(void* const* d_in, const int* in_sizes, int n_in,
                              void* d_out, int out_size, void* d_ws, size_t ws_size,
                              hipStream_t stream) {
    const float* emb = (const float*)d_in[0];
    const float* Wq  = (const float*)d_in[1];
    const float* Wk  = (const float*)d_in[2];
    const float* Wv  = (const float*)d_in[3];
    const int*   w32 = (const int*)d_in[4];

    const int N  = in_sizes[0] / D;   // 100000
    const int E  = in_sizes[4] / 2;   // 800000
    const int NB = (N + 255) / 256;   // 391
    const size_t ND = (size_t)N * D;

    const int* rows = w32;            // validated r10: [2,E], rows = half 0
    const int* cols = w32 + E;

    // Workspace (~59 MB): Q f32 | KVP uint2-pairs | cnt | off | cur | bsum |
    // sc | WfH | WfL
    float*          ws  = (float*)d_ws;
    float*          Q   = ws;
    unsigned int*   KVP = (unsigned int*)(ws + ND);        // ND uint32
    int*   cnt  = (int*)(ws + 2 * ND);
    int*   off  = cnt + N;            // N+1
    int*   cur  = off + N + 1;
    int*   bsum = cur + N;
    int*   sc   = bsum + NB + (NB & 1);   // keep 8B alignment downstream
    unsigned short* WfH = (unsigned short*)(sc + E);       // 24 KB
    unsigned short* WfL = WfH + 12288;                     // 24 KB

    float* out = (float*)d_out;

    (void)hipMemsetAsync(cnt, 0, (size_t)N * sizeof(int), stream);

    // 0) W -> hi/lo MFMA fragment order (48 KB, 48 blocks: 1 elem/thread)
    prep_w_kernel<<<48, 256, 0, stream>>>(Wq, Wk, Wv, WfH, WfL);

    // 1) QKV projection (split-precision MFMA, Wf in LDS, paired outputs)
    qkv_kernel<<<(N + 63) / 64, 256, 0, stream>>>(emb, WfH, WfL, N, Q, KVP);

    // 2) Counting sort of edges by destination (4 dispatches)
    histo_kernel<<<(E + 255) / 256, 256, 0, stream>>>(rows, cnt, E);
    block_sum_kernel<<<NB, 256, 0, stream>>>(cnt, bsum, N);
    block_scan_kernel<<<NB, 256, 0, stream>>>(cnt, bsum, off, cur, N, E, NB);
    scatter_kernel<<<(E + 255) / 256, 256, 0, stream>>>(rows, cols, cur, sc, E);

    // 3) Atomic-free aggregation: one wave per node, 4 edges per wave-step
    aggregate_kernel<<<((size_t)N * 64 + 255) / 256, 256, 0, stream>>>(
        off, sc, Q, KVP, out, N);
}